// Round 8
// baseline (1328.834 us; speedup 1.0000x reference)
//
#include <hip/hip_runtime.h>
#include <hip/hip_fp16.h>

// GCN 2-layer forward on MI355X.
// Bucketed aggregation: one block per 256-dest bucket, LDS fp32 accumulators,
// edges sorted by source within bucket => all co-resident blocks sweep h1/g
// in a synchronized band that fits per-XCD L2.
// d_in: [0]=x (N*128 f32), [1]=edge_index (2*E i32), [2]=W1 (128*64),
//       [3]=b1 (64), [4]=W2 (64*40), [5]=b2 (40)
// d_out: N*40 f32

#define FIN 128
#define H1  64
#define C2  40
#define GP  64            // padded row stride (halves) for g => 128 B lines
#define TILE 8192         // edges per tile
#define BCAP 6144         // bucket capacity (mean 4096, sd ~64)

// ---------- global bucket histogram (bucket = dest >> 8) ----------
__global__ __launch_bounds__(256) void k_hist(const int* __restrict__ col, int E,
                                              int* __restrict__ bucketCnt, int NB) {
    extern __shared__ int lh[];
    int t = threadIdx.x;
    for (int i = t; i < NB; i += 256) lh[i] = 0;
    __syncthreads();
    int base = blockIdx.x * TILE;
    int cnt = min(TILE, E - base);
    for (int i = t; i < cnt; i += 256) atomicAdd(&lh[col[base + i] >> 8], 1);
    __syncthreads();
    for (int b = t; b < NB; b += 256) if (lh[b]) atomicAdd(&bucketCnt[b], lh[b]);
}

// ---------- single-block scan over NB buckets ----------
__global__ __launch_bounds__(512) void k_scan(const int* __restrict__ bucketCnt,
                                              int* __restrict__ rawBase,
                                              int* __restrict__ padBase,
                                              int* __restrict__ gcursor,
                                              float* __restrict__ dinv,
                                              int NB, int N) {
    __shared__ int sr[512], sp[512];
    int t = threadIdx.x;
    int c = (t < NB) ? bucketCnt[t] : 0;
    int p = (t < NB) ? ((c + 7) & ~7) : 0;      // pad each bucket to x8
    sr[t] = c; sp[t] = p;
    __syncthreads();
    for (int off = 1; off < 512; off <<= 1) {
        int a = (t >= off) ? sr[t - off] : 0;
        int b = (t >= off) ? sp[t - off] : 0;
        __syncthreads();
        sr[t] += a; sp[t] += b;
        __syncthreads();
    }
    if (t <= NB) {
        int rex = sr[t] - ((t < NB) ? c : 0);
        int pex = sp[t] - ((t < NB) ? p : 0);
        rawBase[t] = rex;
        padBase[t] = pex;
        if (t < NB) gcursor[t] = rex;
    }
    if (t == 0) dinv[N] = 0.f;                  // sentinel: weight 0
}

// ---------- scatter into bucket-contiguous chunks (packed pairs) ----------
// packed: bits 0..23 = src row, bits 24..31 = dest low 8
__global__ __launch_bounds__(512) void k_scatter(const int* __restrict__ row,
                                                 const int* __restrict__ col,
                                                 int* __restrict__ gcursor,
                                                 int* __restrict__ pairs,
                                                 int E, int NB) {
    __shared__ int2 stage[TILE];         // 64 KB
    __shared__ int lcnt[512];
    __shared__ int lex[512];
    __shared__ int gbase[512];
    int t = threadIdx.x, tile = blockIdx.x;
    int base = tile * TILE;
    int cnt = min(TILE, E - base);

    lcnt[t] = 0;
    __syncthreads();
    for (int i = t; i < cnt; i += 512) atomicAdd(&lcnt[col[base + i] >> 8], 1);
    __syncthreads();

    int myc = lcnt[t];
    lex[t] = myc;
    __syncthreads();
    for (int off = 1; off < 512; off <<= 1) {
        int u = (t >= off) ? lex[t - off] : 0;
        __syncthreads();
        lex[t] += u;
        __syncthreads();
    }
    int ex = lex[t] - myc;
    __syncthreads();
    lex[t] = ex;
    lcnt[t] = ex;
    if (t < NB && myc > 0) gbase[t] = atomicAdd(&gcursor[t], myc);
    __syncthreads();

    for (int i = t; i < cnt; i += 512) {
        int r = row[base + i], c = col[base + i];
        int lpos = atomicAdd(&lcnt[c >> 8], 1);
        stage[lpos] = make_int2(r, c);
    }
    __syncthreads();

    for (int i = t; i < cnt; i += 512) {
        int2 p = stage[i];
        int b = p.y >> 8;
        pairs[gbase[b] + (i - lex[b])] = p.x | ((p.y & 255) << 24);
    }
}

// ---------- per-bucket: sort edges by source (coarse, 256-node bins), dinv ----------
__global__ __launch_bounds__(512) void k_bucket(const int* __restrict__ pairs,
                                                const int* __restrict__ rawBase,
                                                const int* __restrict__ padBase,
                                                float* __restrict__ dinv,
                                                int* __restrict__ esrc,
                                                int N, int NB) {
    __shared__ int sbin[512];
    __shared__ int scur[512];
    __shared__ int dcnt[256];
    __shared__ int outbuf[BCAP];         // 24 KB
    int t = threadIdx.x, b = blockIdx.x;
    int d0 = b << 8;
    int bstart = rawBase[b];
    int cnt = rawBase[b + 1] - bstart;
    int cnt8 = (cnt + 7) & ~7;
    int pstart = padBase[b];

    sbin[t] = 0;
    if (t < 256) dcnt[t] = 0;
    __syncthreads();
    for (int i = t; i < cnt; i += 512) {
        unsigned p = (unsigned)pairs[bstart + i];
        atomicAdd(&sbin[(p & 0xFFFFFF) >> 8], 1);
        atomicAdd(&dcnt[p >> 24], 1);
    }
    __syncthreads();

    int myc = sbin[t];
    scur[t] = myc;
    __syncthreads();
    for (int off = 1; off < 512; off <<= 1) {
        int u = (t >= off) ? scur[t - off] : 0;
        __syncthreads();
        scur[t] += u;
        __syncthreads();
    }
    int ex = scur[t] - myc;
    __syncthreads();
    scur[t] = ex;                        // cursor per src-bin
    __syncthreads();

    for (int i = t; i < cnt; i += 512) {
        int p = pairs[bstart + i];
        int pos = atomicAdd(&scur[((unsigned)p & 0xFFFFFF) >> 8], 1);
        outbuf[pos] = p;
    }
    // sentinel pad: src = N (dinv 0), dest 0
    for (int i = cnt + t; i < cnt8; i += 512) outbuf[i] = N;
    __syncthreads();

    for (int i = t; i < cnt8; i += 512) esrc[pstart + i] = outbuf[i];

    if (t < 256) {
        int node = d0 + t;
        if (node < N) dinv[node] = rsqrtf((float)dcnt[t] + 1.0f);
    }
}

// ---------- GEMM1: h1 = fp16(x @ W1), 64x64 tile, 4x4/thread ----------
__global__ __launch_bounds__(256) void k_gemm1(const float* __restrict__ x,
                                               const float* __restrict__ W1,
                                               __half* __restrict__ h1, int N) {
    __shared__ float Ws[FIN * H1];        // 32 KB, [k][o]
    __shared__ float xs[64][FIN + 4];
    int t = threadIdx.x;
    int node0 = blockIdx.x * 64;

    const float4* W4 = (const float4*)W1;
    float4* Ws4 = (float4*)Ws;
#pragma unroll
    for (int j = 0; j < 8; ++j) Ws4[t + j * 256] = W4[t + j * 256];

    const float4* x4 = (const float4*)x;
#pragma unroll
    for (int j = 0; j < 8; ++j) {
        int idx = t + j * 256;
        int r = idx >> 5, kq = idx & 31;
        int node = node0 + r; if (node >= N) node = N - 1;
        float4 v = x4[(size_t)node * 32 + kq];
        *(float4*)&xs[r][kq * 4] = v;
    }
    __syncthreads();

    int og = t & 15, ng = t >> 4;
    int o0 = og * 4, n0 = ng * 4;
    float acc[4][4];
#pragma unroll
    for (int i = 0; i < 4; ++i)
#pragma unroll
        for (int j = 0; j < 4; ++j) acc[i][j] = 0.f;

#pragma unroll 8
    for (int k = 0; k < FIN; ++k) {
        float a0 = xs[n0 + 0][k], a1 = xs[n0 + 1][k];
        float a2 = xs[n0 + 2][k], a3 = xs[n0 + 3][k];
        float4 w = *(const float4*)&Ws[k * H1 + o0];
        acc[0][0] += a0 * w.x; acc[0][1] += a0 * w.y; acc[0][2] += a0 * w.z; acc[0][3] += a0 * w.w;
        acc[1][0] += a1 * w.x; acc[1][1] += a1 * w.y; acc[1][2] += a1 * w.z; acc[1][3] += a1 * w.w;
        acc[2][0] += a2 * w.x; acc[2][1] += a2 * w.y; acc[2][2] += a2 * w.z; acc[2][3] += a2 * w.w;
        acc[3][0] += a3 * w.x; acc[3][1] += a3 * w.y; acc[3][2] += a3 * w.z; acc[3][3] += a3 * w.w;
    }

#pragma unroll
    for (int i = 0; i < 4; ++i) {
        int node = node0 + n0 + i;
        if (node < N) {
            union { __half h[4]; uint2 u; } pk;
            pk.h[0] = __float2half_rn(acc[i][0]);
            pk.h[1] = __float2half_rn(acc[i][1]);
            pk.h[2] = __float2half_rn(acc[i][2]);
            pk.h[3] = __float2half_rn(acc[i][3]);
            *(uint2*)&h1[(size_t)node * H1 + o0] = pk.u;
        }
    }
}

// ---------- agg1 bucketed: block = 256-dest bucket, LDS fp32 acc, src-sorted ----------
__global__ __launch_bounds__(512) void k_agg1B(const int* __restrict__ padBase,
                                               const int* __restrict__ esrc,
                                               const __half* __restrict__ h1,
                                               const float* __restrict__ dinv,
                                               const float* __restrict__ b1,
                                               float* __restrict__ agg, int N) {
    __shared__ float acc[256 * H1];      // 64 KB
    __shared__ float ldinv[256];
    int t = threadIdx.x, b = blockIdx.x;
    int d0 = b << 8;
    int pstart = padBase[b];
    int cnt8 = padBase[b + 1] - pstart;
    const int* ep = esrc + pstart;

    for (int i = t; i < 256 * H1; i += 512) acc[i] = 0.f;
    if (t < 256) {
        int node = d0 + t;
        ldinv[t] = (node < N) ? dinv[node] : 0.f;
    }
    __syncthreads();

    int wv = t >> 6, lane = t & 63;
    float b1v = b1[lane];

    for (int i = wv * 8; i < cnt8; i += 64) {
        int4 pa = *(const int4*)&ep[i];
        int4 pb = *(const int4*)&ep[i + 4];
        int s0 = pa.x & 0xFFFFFF, s1 = pa.y & 0xFFFFFF, s2 = pa.z & 0xFFFFFF, s3 = pa.w & 0xFFFFFF;
        int s4 = pb.x & 0xFFFFFF, s5 = pb.y & 0xFFFFFF, s6 = pb.z & 0xFFFFFF, s7 = pb.w & 0xFFFFFF;
        int dA = (unsigned)pa.x >> 24, dB = (unsigned)pa.y >> 24, dC = (unsigned)pa.z >> 24, dD = (unsigned)pa.w >> 24;
        int dE = (unsigned)pb.x >> 24, dF = (unsigned)pb.y >> 24, dG = (unsigned)pb.z >> 24, dH = (unsigned)pb.w >> 24;
        float w0 = dinv[s0] * ldinv[dA], w1 = dinv[s1] * ldinv[dB];
        float w2 = dinv[s2] * ldinv[dC], w3 = dinv[s3] * ldinv[dD];
        float w4 = dinv[s4] * ldinv[dE], w5 = dinv[s5] * ldinv[dF];
        float w6 = dinv[s6] * ldinv[dG], w7 = dinv[s7] * ldinv[dH];
        float v0 = __half2float(h1[(size_t)s0 * H1 + lane]);
        float v1 = __half2float(h1[(size_t)s1 * H1 + lane]);
        float v2 = __half2float(h1[(size_t)s2 * H1 + lane]);
        float v3 = __half2float(h1[(size_t)s3 * H1 + lane]);
        float v4 = __half2float(h1[(size_t)s4 * H1 + lane]);
        float v5 = __half2float(h1[(size_t)s5 * H1 + lane]);
        float v6 = __half2float(h1[(size_t)s6 * H1 + lane]);
        float v7 = __half2float(h1[(size_t)s7 * H1 + lane]);
        atomicAdd(&acc[dA * H1 + lane], w0 * v0);
        atomicAdd(&acc[dB * H1 + lane], w1 * v1);
        atomicAdd(&acc[dC * H1 + lane], w2 * v2);
        atomicAdd(&acc[dD * H1 + lane], w3 * v3);
        atomicAdd(&acc[dE * H1 + lane], w4 * v4);
        atomicAdd(&acc[dF * H1 + lane], w5 * v5);
        atomicAdd(&acc[dG * H1 + lane], w6 * v6);
        atomicAdd(&acc[dH * H1 + lane], w7 * v7);
    }
    __syncthreads();

    // epilogue: self-loop + bias, write agg1 (fp32)
    for (int j = 0; j < 32; ++j) {
        int d = wv * 32 + j;
        int node = d0 + d;
        if (node < N) {
            float dc = ldinv[d];
            float v = acc[d * H1 + lane] + dc * dc * __half2float(h1[(size_t)node * H1 + lane]) + b1v;
            agg[(size_t)node * H1 + lane] = v;
        }
    }
}

// ---------- GEMM2: g = fp16(relu(agg1) @ W2), padded row stride GP ----------
__global__ __launch_bounds__(256) void k_gemm2(const float* __restrict__ agg1,
                                               const float* __restrict__ W2,
                                               __half* __restrict__ g, int N) {
    __shared__ float Ws[H1 * C2];
    __shared__ float hs[64][H1 + 4];
    int t = threadIdx.x;
    int node0 = blockIdx.x * 64;

    const float4* W4 = (const float4*)W2;
    float4* Ws4 = (float4*)Ws;
    for (int i = t; i < 640; i += 256) Ws4[i] = W4[i];

    const float4* a4 = (const float4*)agg1;
#pragma unroll
    for (int j = 0; j < 4; ++j) {
        int idx = t + j * 256;
        int r = idx >> 4, kq = idx & 15;
        int node = node0 + r; if (node >= N) node = N - 1;
        float4 v = a4[(size_t)node * 16 + kq];
        v.x = fmaxf(v.x, 0.f); v.y = fmaxf(v.y, 0.f);
        v.z = fmaxf(v.z, 0.f); v.w = fmaxf(v.w, 0.f);
        *(float4*)&hs[r][kq * 4] = v;
    }
    __syncthreads();

    int og = t & 15, ng = t >> 4;
    int o0 = og * 4, n0 = ng * 4;
    int o0c = (o0 <= 36) ? o0 : 36;
    float acc[4][4];
#pragma unroll
    for (int i = 0; i < 4; ++i)
#pragma unroll
        for (int j = 0; j < 4; ++j) acc[i][j] = 0.f;

#pragma unroll 8
    for (int k = 0; k < H1; ++k) {
        float a0 = hs[n0 + 0][k], a1 = hs[n0 + 1][k];
        float a2 = hs[n0 + 2][k], a3 = hs[n0 + 3][k];
        float4 w = *(const float4*)&Ws[k * C2 + o0c];
        acc[0][0] += a0 * w.x; acc[0][1] += a0 * w.y; acc[0][2] += a0 * w.z; acc[0][3] += a0 * w.w;
        acc[1][0] += a1 * w.x; acc[1][1] += a1 * w.y; acc[1][2] += a1 * w.z; acc[1][3] += a1 * w.w;
        acc[2][0] += a2 * w.x; acc[2][1] += a2 * w.y; acc[2][2] += a2 * w.z; acc[2][3] += a2 * w.w;
        acc[3][0] += a3 * w.x; acc[3][1] += a3 * w.y; acc[3][2] += a3 * w.z; acc[3][3] += a3 * w.w;
    }

    if (o0 < C2) {
#pragma unroll
        for (int i = 0; i < 4; ++i) {
            int node = node0 + n0 + i;
            if (node < N) {
                union { __half h[4]; uint2 u; } pk;
                pk.h[0] = __float2half_rn(acc[i][0]);
                pk.h[1] = __float2half_rn(acc[i][1]);
                pk.h[2] = __float2half_rn(acc[i][2]);
                pk.h[3] = __float2half_rn(acc[i][3]);
                *(uint2*)&g[(size_t)node * GP + o0] = pk.u;
            }
        }
    }
}

// ---------- agg2 bucketed: lanes 0..39 = features ----------
__global__ __launch_bounds__(512) void k_agg2B(const int* __restrict__ padBase,
                                               const int* __restrict__ esrc,
                                               const __half* __restrict__ g,
                                               const float* __restrict__ dinv,
                                               const float* __restrict__ b2,
                                               float* __restrict__ out, int N) {
    __shared__ float acc[256 * C2];      // 40 KB
    __shared__ float ldinv[256];
    int t = threadIdx.x, b = blockIdx.x;
    int d0 = b << 8;
    int pstart = padBase[b];
    int cnt8 = padBase[b + 1] - pstart;
    const int* ep = esrc + pstart;

    for (int i = t; i < 256 * C2; i += 512) acc[i] = 0.f;
    if (t < 256) {
        int node = d0 + t;
        ldinv[t] = (node < N) ? dinv[node] : 0.f;
    }
    __syncthreads();

    int wv = t >> 6, lane = t & 63;
    bool active = lane < C2;
    float b2v = b2[active ? lane : 0];

    for (int i = wv * 8; i < cnt8; i += 64) {
        int4 pa = *(const int4*)&ep[i];
        int4 pb = *(const int4*)&ep[i + 4];
        int s0 = pa.x & 0xFFFFFF, s1 = pa.y & 0xFFFFFF, s2 = pa.z & 0xFFFFFF, s3 = pa.w & 0xFFFFFF;
        int s4 = pb.x & 0xFFFFFF, s5 = pb.y & 0xFFFFFF, s6 = pb.z & 0xFFFFFF, s7 = pb.w & 0xFFFFFF;
        int dA = (unsigned)pa.x >> 24, dB = (unsigned)pa.y >> 24, dC = (unsigned)pa.z >> 24, dD = (unsigned)pa.w >> 24;
        int dE = (unsigned)pb.x >> 24, dF = (unsigned)pb.y >> 24, dG = (unsigned)pb.z >> 24, dH = (unsigned)pb.w >> 24;
        float w0 = dinv[s0] * ldinv[dA], w1 = dinv[s1] * ldinv[dB];
        float w2 = dinv[s2] * ldinv[dC], w3 = dinv[s3] * ldinv[dD];
        float w4 = dinv[s4] * ldinv[dE], w5 = dinv[s5] * ldinv[dF];
        float w6 = dinv[s6] * ldinv[dG], w7 = dinv[s7] * ldinv[dH];
        if (active) {
            float v0 = __half2float(g[(size_t)s0 * GP + lane]);
            float v1 = __half2float(g[(size_t)s1 * GP + lane]);
            float v2 = __half2float(g[(size_t)s2 * GP + lane]);
            float v3 = __half2float(g[(size_t)s3 * GP + lane]);
            float v4 = __half2float(g[(size_t)s4 * GP + lane]);
            float v5 = __half2float(g[(size_t)s5 * GP + lane]);
            float v6 = __half2float(g[(size_t)s6 * GP + lane]);
            float v7 = __half2float(g[(size_t)s7 * GP + lane]);
            atomicAdd(&acc[dA * C2 + lane], w0 * v0);
            atomicAdd(&acc[dB * C2 + lane], w1 * v1);
            atomicAdd(&acc[dC * C2 + lane], w2 * v2);
            atomicAdd(&acc[dD * C2 + lane], w3 * v3);
            atomicAdd(&acc[dE * C2 + lane], w4 * v4);
            atomicAdd(&acc[dF * C2 + lane], w5 * v5);
            atomicAdd(&acc[dG * C2 + lane], w6 * v6);
            atomicAdd(&acc[dH * C2 + lane], w7 * v7);
        }
    }
    __syncthreads();

    for (int j = 0; j < 32; ++j) {
        int d = wv * 32 + j;
        int node = d0 + d;
        if (node < N && active) {
            float dc = ldinv[d];
            float v = acc[d * C2 + lane] + dc * dc * __half2float(g[(size_t)node * GP + lane]) + b2v;
            out[(size_t)node * C2 + lane] = v;
        }
    }
}

extern "C" void kernel_launch(void* const* d_in, const int* in_sizes, int n_in,
                              void* d_out, int out_size, void* d_ws, size_t ws_size,
                              hipStream_t stream) {
    const float* x   = (const float*)d_in[0];
    const int*   ei  = (const int*)d_in[1];
    const float* W1  = (const float*)d_in[2];
    const float* b1  = (const float*)d_in[3];
    const float* W2  = (const float*)d_in[4];
    const float* b2  = (const float*)d_in[5];
    float* out = (float*)d_out;

    const int N = in_sizes[0] / FIN;       // 100000
    const int E = in_sizes[1] / 2;         // 1600000
    const int* row = ei;
    const int* col = ei + E;

    const int NB = (N + 255) >> 8;         // 391 buckets
    const int T  = (E + TILE - 1) / TILE;  // 196 tiles
    const int EP = E + NB * 8 + 64;        // padded esrc capacity

    // workspace layout
    char* ws = (char*)d_ws;
    size_t off = 0;
    int*    bucketCnt = (int*)(ws + off);    off += (size_t)NB * 4;
    int*    rawBase   = (int*)(ws + off);    off += (size_t)(NB + 1) * 4;
    int*    padBase   = (int*)(ws + off);    off += (size_t)(NB + 1) * 4;
    int*    gcursor   = (int*)(ws + off);    off += (size_t)NB * 4;
    float*  dinv      = (float*)(ws + off);  off += (size_t)(N + 1) * 4;
    int*    pairs     = (int*)(ws + off);    off += (size_t)E * 4;
    int*    esrc      = (int*)(ws + off);    off += (size_t)EP * 4;
    __half* h1        = (__half*)(ws + off); off += (size_t)(N + 1) * H1 * 2;
    float*  agg1      = (float*)(ws + off);  off += (size_t)N * H1 * 4;
    __half* g         = (__half*)(ws + off); off += (size_t)(N + 1) * GP * 2;

    hipMemsetAsync(bucketCnt, 0, (size_t)NB * 4, stream);

    int gblocks = (N + 63) / 64;
    k_gemm1<<<gblocks, 256, 0, stream>>>(x, W1, h1, N);

    // CSR-free build: hist -> scan -> chunk-claim scatter -> per-bucket src-sort
    k_hist<<<T, 256, NB * 4, stream>>>(col, E, bucketCnt, NB);
    k_scan<<<1, 512, 0, stream>>>(bucketCnt, rawBase, padBase, gcursor, dinv, NB, N);
    k_scatter<<<T, 512, 0, stream>>>(row, col, gcursor, pairs, E, NB);
    k_bucket<<<NB, 512, 0, stream>>>(pairs, rawBase, padBase, dinv, esrc, N, NB);

    // layer 1 (bucketed aggregation)
    k_agg1B<<<NB, 512, 0, stream>>>(padBase, esrc, h1, dinv, b1, agg1, N);

    // layer 2
    k_gemm2<<<gblocks, 256, 0, stream>>>(agg1, W2, g, N);
    k_agg2B<<<NB, 512, 0, stream>>>(padBase, esrc, g, dinv, b2, out, N);
}

// Round 9
// 315.096 us; speedup vs baseline: 4.2172x; 4.2172x over previous
//
#include <hip/hip_runtime.h>
#include <hip/hip_fp16.h>

// GCN 2-layer forward on MI355X.
// R7 gather structure + precomputed fp16 edge weights (ew) to cut VMEM
// transactions in the agg loops. Counting-sort CSR build (chunk-claim),
// rows padded to x4 with weight-0 sentinel, fp16 line-aligned gather arrays.
// d_in: [0]=x (N*128 f32), [1]=edge_index (2*E i32), [2]=W1 (128*64),
//       [3]=b1 (64), [4]=W2 (64*40), [5]=b2 (40)
// d_out: N*40 f32

#define FIN 128
#define H1  64
#define C2  40
#define GP  64            // padded row stride (halves) for g => 128 B lines
#define TILE 4096         // edges per tile (392 tiles => full CU coverage)
#define BCAP 6144         // padded bucket capacity (mean ~4480, sd 64)

// ---------- global bucket histogram (bucket = dest >> 8) ----------
__global__ __launch_bounds__(256) void k_hist(const int* __restrict__ col, int E,
                                              int* __restrict__ bucketCnt, int NB) {
    extern __shared__ int lh[];
    int t = threadIdx.x;
    for (int i = t; i < NB; i += 256) lh[i] = 0;
    __syncthreads();
    int base = blockIdx.x * TILE;
    int cnt = min(TILE, E - base);
    for (int i = t; i < cnt; i += 256) atomicAdd(&lh[col[base + i] >> 8], 1);
    __syncthreads();
    for (int b = t; b < NB; b += 256) if (lh[b]) atomicAdd(&bucketCnt[b], lh[b]);
}

// ---------- single-block scan over NB buckets: raw & padded bases ----------
__global__ __launch_bounds__(512) void k_scan(const int* __restrict__ bucketCnt,
                                              int* __restrict__ rawBase,
                                              int* __restrict__ padBase,
                                              int* __restrict__ gcursor,
                                              float* __restrict__ dinv,
                                              int NB, int N) {
    __shared__ int sr[512], sp[512];
    int t = threadIdx.x;
    int c = (t < NB) ? bucketCnt[t] : 0;
    int p = (t < NB) ? (((c + 3) & ~3) + 1024) : 0;   // room for per-dest x4 pad
    sr[t] = c; sp[t] = p;
    __syncthreads();
    for (int off = 1; off < 512; off <<= 1) {
        int a = (t >= off) ? sr[t - off] : 0;
        int b = (t >= off) ? sp[t - off] : 0;
        __syncthreads();
        sr[t] += a; sp[t] += b;
        __syncthreads();
    }
    if (t <= NB) {
        int rex = sr[t] - ((t < NB) ? c : 0);   // exclusive (t==NB -> total)
        int pex = sp[t] - ((t < NB) ? p : 0);
        rawBase[t] = rex;
        padBase[t] = pex;
        if (t < NB) gcursor[t] = rex;
    }
    if (t == 0) dinv[N] = 0.f;                  // sentinel: weight 0
}

// ---------- scatter into bucket-contiguous chunks (packed pairs) ----------
// packed: bits 0..23 = src row, bits 24..31 = dest low 8
__global__ __launch_bounds__(512) void k_scatter(const int* __restrict__ row,
                                                 const int* __restrict__ col,
                                                 int* __restrict__ gcursor,
                                                 int* __restrict__ pairs,
                                                 int E, int NB) {
    __shared__ int2 stage[TILE];         // 32 KB
    __shared__ int lcnt[512];
    __shared__ int lex[512];
    __shared__ int gbase[512];
    int t = threadIdx.x, tile = blockIdx.x;
    int base = tile * TILE;
    int cnt = min(TILE, E - base);

    lcnt[t] = 0;
    __syncthreads();
    for (int i = t; i < cnt; i += 512) atomicAdd(&lcnt[col[base + i] >> 8], 1);
    __syncthreads();

    int myc = lcnt[t];
    lex[t] = myc;
    __syncthreads();
    for (int off = 1; off < 512; off <<= 1) {
        int u = (t >= off) ? lex[t - off] : 0;
        __syncthreads();
        lex[t] += u;
        __syncthreads();
    }
    int ex = lex[t] - myc;
    __syncthreads();
    lex[t] = ex;
    lcnt[t] = ex;                         // local cursor
    if (t < NB && myc > 0) gbase[t] = atomicAdd(&gcursor[t], myc);
    __syncthreads();

    for (int i = t; i < cnt; i += 512) {
        int r = row[base + i], c = col[base + i];
        int lpos = atomicAdd(&lcnt[c >> 8], 1);
        stage[lpos] = make_int2(r, c);
    }
    __syncthreads();

    for (int i = t; i < cnt; i += 512) {
        int2 p = stage[i];
        int b = p.y >> 8;
        pairs[gbase[b] + (i - lex[b])] = p.x | ((p.y & 255) << 24);
    }
}

// ---------- per-bucket final sort by dest; padded esrc segments ----------
__global__ __launch_bounds__(256) void k_bucket(const int* __restrict__ pairs,
                                                const int* __restrict__ rawBase,
                                                const int* __restrict__ padBase,
                                                int* __restrict__ rowptr,
                                                int* __restrict__ deg,
                                                float* __restrict__ dinv,
                                                int* __restrict__ esrc,
                                                int N, int NB) {
    __shared__ int dcnt[256];
    __shared__ int sr[256], sp[256];
    __shared__ int cur[256];
    __shared__ int outbuf[BCAP];         // 24 KB
    int t = threadIdx.x, b = blockIdx.x;
    int d0 = b << 8;
    int nd = min(256, N - d0);
    int bstart = rawBase[b];
    int cnt = rawBase[b + 1] - bstart;
    int pstart = padBase[b];

    dcnt[t] = 0;
    __syncthreads();
    for (int i = t; i < cnt; i += 256) {
        unsigned p = (unsigned)pairs[bstart + i];
        atomicAdd(&dcnt[p >> 24], 1);
    }
    __syncthreads();

    int myc = dcnt[t];
    int myp = (myc + 3) & ~3;            // padded per-dest count
    sr[t] = myc; sp[t] = myp;
    __syncthreads();
    for (int off = 1; off < 256; off <<= 1) {
        int a = (t >= off) ? sr[t - off] : 0;
        int c2 = (t >= off) ? sp[t - off] : 0;
        __syncthreads();
        sr[t] += a; sp[t] += c2;
        __syncthreads();
    }
    int pex = sp[t] - myp;               // exclusive padded offset
    int pcnt = sp[255];                  // total padded content
    __syncthreads();
    cur[t] = pex;
    if (t < nd) {
        int node = d0 + t;
        rowptr[node] = pstart + pex;
        deg[node] = myc;
        dinv[node] = rsqrtf((float)myc + 1.0f);
    }
    __syncthreads();

    if (pcnt <= BCAP) {
        for (int i = t; i < cnt; i += 256) {
            unsigned p = (unsigned)pairs[bstart + i];
            int lpos = atomicAdd(&cur[p >> 24], 1);
            outbuf[lpos] = (int)(p & 0xFFFFFF);
        }
        __syncthreads();
        // fill per-dest pad slots with sentinel N (weight 0)
        for (int j = myc; j < myp; ++j) outbuf[pex + j] = N;
        __syncthreads();
        for (int i = t; i < pcnt; i += 256) esrc[pstart + i] = outbuf[i];
    } else {
        for (int i = t; i < cnt; i += 256) {
            unsigned p = (unsigned)pairs[bstart + i];
            int lpos = atomicAdd(&cur[p >> 24], 1);
            esrc[pstart + lpos] = (int)(p & 0xFFFFFF);
        }
        __syncthreads();
        for (int j = myc; j < myp; ++j) esrc[pstart + pex + j] = N;
    }
}

// ---------- ew: per-edge weight dinv[src]*dinv[dst], fp16, coalesced ----------
// one wave per dest node; lanes stride the node's edge list
__global__ __launch_bounds__(256) void k_ew(const int* __restrict__ rowptr,
                                            const int* __restrict__ deg,
                                            const int* __restrict__ esrc,
                                            const float* __restrict__ dinv,
                                            __half* __restrict__ ew, int N) {
    int w = (blockIdx.x * blockDim.x + threadIdx.x) >> 6;
    int lane = threadIdx.x & 63;
    if (w >= N) return;
    int start = rowptr[w];
    int d4 = (deg[w] + 3) & ~3;
    float dc = dinv[w];
    for (int j = lane; j < d4; j += 64) {
        int s = esrc[start + j];
        ew[start + j] = __float2half_rn(dinv[s] * dc);   // pad: dinv[N]=0 -> 0
    }
}

// ---------- GEMM1: h1 = fp16(x @ W1), 64x64 tile, 4x4/thread ----------
__global__ __launch_bounds__(256) void k_gemm1(const float* __restrict__ x,
                                               const float* __restrict__ W1,
                                               __half* __restrict__ h1, int N) {
    __shared__ float Ws[FIN * H1];        // 32 KB, [k][o]
    __shared__ float xs[64][FIN + 4];
    int t = threadIdx.x;
    int node0 = blockIdx.x * 64;

    const float4* W4 = (const float4*)W1;
    float4* Ws4 = (float4*)Ws;
#pragma unroll
    for (int j = 0; j < 8; ++j) Ws4[t + j * 256] = W4[t + j * 256];

    const float4* x4 = (const float4*)x;
#pragma unroll
    for (int j = 0; j < 8; ++j) {
        int idx = t + j * 256;
        int r = idx >> 5, kq = idx & 31;
        int node = node0 + r; if (node >= N) node = N - 1;
        float4 v = x4[(size_t)node * 32 + kq];
        *(float4*)&xs[r][kq * 4] = v;
    }
    __syncthreads();

    int og = t & 15, ng = t >> 4;
    int o0 = og * 4, n0 = ng * 4;
    float acc[4][4];
#pragma unroll
    for (int i = 0; i < 4; ++i)
#pragma unroll
        for (int j = 0; j < 4; ++j) acc[i][j] = 0.f;

#pragma unroll 8
    for (int k = 0; k < FIN; ++k) {
        float a0 = xs[n0 + 0][k], a1 = xs[n0 + 1][k];
        float a2 = xs[n0 + 2][k], a3 = xs[n0 + 3][k];
        float4 w = *(const float4*)&Ws[k * H1 + o0];
        acc[0][0] += a0 * w.x; acc[0][1] += a0 * w.y; acc[0][2] += a0 * w.z; acc[0][3] += a0 * w.w;
        acc[1][0] += a1 * w.x; acc[1][1] += a1 * w.y; acc[1][2] += a1 * w.z; acc[1][3] += a1 * w.w;
        acc[2][0] += a2 * w.x; acc[2][1] += a2 * w.y; acc[2][2] += a2 * w.z; acc[2][3] += a2 * w.w;
        acc[3][0] += a3 * w.x; acc[3][1] += a3 * w.y; acc[3][2] += a3 * w.z; acc[3][3] += a3 * w.w;
    }

#pragma unroll
    for (int i = 0; i < 4; ++i) {
        int node = node0 + n0 + i;
        if (node < N) {
            union { __half h[4]; uint2 u; } pk;
            pk.h[0] = __float2half_rn(acc[i][0]);
            pk.h[1] = __float2half_rn(acc[i][1]);
            pk.h[2] = __float2half_rn(acc[i][2]);
            pk.h[3] = __float2half_rn(acc[i][3]);
            *(uint2*)&h1[(size_t)node * H1 + o0] = pk.u;
        }
    }
}

// 8B = 4 halves
struct h4v { __half2 a, b; };

// ---------- agg1: wave per node, lane = feature; ew-weighted, tail-free ----------
__global__ __launch_bounds__(256) void k_agg1(const int* __restrict__ rowptr,
                                              const int* __restrict__ deg,
                                              const int* __restrict__ esrc,
                                              const __half* __restrict__ ew,
                                              const __half* __restrict__ h1,
                                              const float* __restrict__ dinv,
                                              const float* __restrict__ b1,
                                              float* __restrict__ agg, int N) {
    int w = (blockIdx.x * blockDim.x + threadIdx.x) >> 6;
    int lane = threadIdx.x & 63;
    if (w >= N) return;
    int start = rowptr[w], d = deg[w];
    int d4 = (d + 3) & ~3;
    float dc = dinv[w];
    float acc = dc * dc * __half2float(h1[(size_t)w * H1 + lane]);
    int i = 0;
    for (; i + 8 <= d4; i += 8) {
        int4 ra = *(const int4*)&esrc[start + i];
        int4 rb = *(const int4*)&esrc[start + i + 4];
        h4v wa = *(const h4v*)&ew[start + i];
        h4v wb = *(const h4v*)&ew[start + i + 4];
        float2 wa0 = __half22float2(wa.a), wa1 = __half22float2(wa.b);
        float2 wb0 = __half22float2(wb.a), wb1 = __half22float2(wb.b);
        float v0 = __half2float(h1[(size_t)ra.x * H1 + lane]);
        float v1 = __half2float(h1[(size_t)ra.y * H1 + lane]);
        float v2 = __half2float(h1[(size_t)ra.z * H1 + lane]);
        float v3 = __half2float(h1[(size_t)ra.w * H1 + lane]);
        float v4 = __half2float(h1[(size_t)rb.x * H1 + lane]);
        float v5 = __half2float(h1[(size_t)rb.y * H1 + lane]);
        float v6 = __half2float(h1[(size_t)rb.z * H1 + lane]);
        float v7 = __half2float(h1[(size_t)rb.w * H1 + lane]);
        acc += wa0.x * v0 + wa0.y * v1 + wa1.x * v2 + wa1.y * v3;
        acc += wb0.x * v4 + wb0.y * v5 + wb1.x * v6 + wb1.y * v7;
    }
    if (i < d4) {
        int4 ra = *(const int4*)&esrc[start + i];
        h4v wa = *(const h4v*)&ew[start + i];
        float2 wa0 = __half22float2(wa.a), wa1 = __half22float2(wa.b);
        float v0 = __half2float(h1[(size_t)ra.x * H1 + lane]);
        float v1 = __half2float(h1[(size_t)ra.y * H1 + lane]);
        float v2 = __half2float(h1[(size_t)ra.z * H1 + lane]);
        float v3 = __half2float(h1[(size_t)ra.w * H1 + lane]);
        acc += wa0.x * v0 + wa0.y * v1 + wa1.x * v2 + wa1.y * v3;
    }
    agg[(size_t)w * H1 + lane] = acc + b1[lane];
}

// ---------- GEMM2: g = fp16(relu(agg1) @ W2), padded row stride GP ----------
__global__ __launch_bounds__(256) void k_gemm2(const float* __restrict__ agg1,
                                               const float* __restrict__ W2,
                                               __half* __restrict__ g, int N) {
    __shared__ float Ws[H1 * C2];
    __shared__ float hs[64][H1 + 4];
    int t = threadIdx.x;
    int node0 = blockIdx.x * 64;

    const float4* W4 = (const float4*)W2;
    float4* Ws4 = (float4*)Ws;
    for (int i = t; i < 640; i += 256) Ws4[i] = W4[i];

    const float4* a4 = (const float4*)agg1;
#pragma unroll
    for (int j = 0; j < 4; ++j) {
        int idx = t + j * 256;
        int r = idx >> 4, kq = idx & 15;
        int node = node0 + r; if (node >= N) node = N - 1;
        float4 v = a4[(size_t)node * 16 + kq];
        v.x = fmaxf(v.x, 0.f); v.y = fmaxf(v.y, 0.f);
        v.z = fmaxf(v.z, 0.f); v.w = fmaxf(v.w, 0.f);
        *(float4*)&hs[r][kq * 4] = v;
    }
    __syncthreads();

    int og = t & 15, ng = t >> 4;
    int o0 = og * 4, n0 = ng * 4;
    int o0c = (o0 <= 36) ? o0 : 36;
    float acc[4][4];
#pragma unroll
    for (int i = 0; i < 4; ++i)
#pragma unroll
        for (int j = 0; j < 4; ++j) acc[i][j] = 0.f;

#pragma unroll 8
    for (int k = 0; k < H1; ++k) {
        float a0 = hs[n0 + 0][k], a1 = hs[n0 + 1][k];
        float a2 = hs[n0 + 2][k], a3 = hs[n0 + 3][k];
        float4 w = *(const float4*)&Ws[k * C2 + o0c];
        acc[0][0] += a0 * w.x; acc[0][1] += a0 * w.y; acc[0][2] += a0 * w.z; acc[0][3] += a0 * w.w;
        acc[1][0] += a1 * w.x; acc[1][1] += a1 * w.y; acc[1][2] += a1 * w.z; acc[1][3] += a1 * w.w;
        acc[2][0] += a2 * w.x; acc[2][1] += a2 * w.y; acc[2][2] += a2 * w.z; acc[2][3] += a2 * w.w;
        acc[3][0] += a3 * w.x; acc[3][1] += a3 * w.y; acc[3][2] += a3 * w.z; acc[3][3] += a3 * w.w;
    }

    if (o0 < C2) {
#pragma unroll
        for (int i = 0; i < 4; ++i) {
            int node = node0 + n0 + i;
            if (node < N) {
                union { __half h[4]; uint2 u; } pk;
                pk.h[0] = __float2half_rn(acc[i][0]);
                pk.h[1] = __float2half_rn(acc[i][1]);
                pk.h[2] = __float2half_rn(acc[i][2]);
                pk.h[3] = __float2half_rn(acc[i][3]);
                *(uint2*)&g[(size_t)node * GP + o0] = pk.u;
            }
        }
    }
}

// ---------- agg2: wave per node, lanes 0..39; ew-weighted ----------
__global__ __launch_bounds__(256) void k_agg2(const int* __restrict__ rowptr,
                                              const int* __restrict__ deg,
                                              const int* __restrict__ esrc,
                                              const __half* __restrict__ ew,
                                              const __half* __restrict__ g,
                                              const float* __restrict__ dinv,
                                              const float* __restrict__ b2,
                                              float* __restrict__ out, int N) {
    int w = (blockIdx.x * blockDim.x + threadIdx.x) >> 6;
    int lane = threadIdx.x & 63;
    if (w >= N || lane >= C2) return;
    int start = rowptr[w], d = deg[w];
    int d4 = (d + 3) & ~3;
    float dc = dinv[w];
    float acc = dc * dc * __half2float(g[(size_t)w * GP + lane]);
    int i = 0;
    for (; i + 8 <= d4; i += 8) {
        int4 ra = *(const int4*)&esrc[start + i];
        int4 rb = *(const int4*)&esrc[start + i + 4];
        h4v wa = *(const h4v*)&ew[start + i];
        h4v wb = *(const h4v*)&ew[start + i + 4];
        float2 wa0 = __half22float2(wa.a), wa1 = __half22float2(wa.b);
        float2 wb0 = __half22float2(wb.a), wb1 = __half22float2(wb.b);
        float v0 = __half2float(g[(size_t)ra.x * GP + lane]);
        float v1 = __half2float(g[(size_t)ra.y * GP + lane]);
        float v2 = __half2float(g[(size_t)ra.z * GP + lane]);
        float v3 = __half2float(g[(size_t)ra.w * GP + lane]);
        float v4 = __half2float(g[(size_t)rb.x * GP + lane]);
        float v5 = __half2float(g[(size_t)rb.y * GP + lane]);
        float v6 = __half2float(g[(size_t)rb.z * GP + lane]);
        float v7 = __half2float(g[(size_t)rb.w * GP + lane]);
        acc += wa0.x * v0 + wa0.y * v1 + wa1.x * v2 + wa1.y * v3;
        acc += wb0.x * v4 + wb0.y * v5 + wb1.x * v6 + wb1.y * v7;
    }
    if (i < d4) {
        int4 ra = *(const int4*)&esrc[start + i];
        h4v wa = *(const h4v*)&ew[start + i];
        float2 wa0 = __half22float2(wa.a), wa1 = __half22float2(wa.b);
        float v0 = __half2float(g[(size_t)ra.x * GP + lane]);
        float v1 = __half2float(g[(size_t)ra.y * GP + lane]);
        float v2 = __half2float(g[(size_t)ra.z * GP + lane]);
        float v3 = __half2float(g[(size_t)ra.w * GP + lane]);
        acc += wa0.x * v0 + wa0.y * v1 + wa1.x * v2 + wa1.y * v3;
    }
    out[(size_t)w * C2 + lane] = acc + b2[lane];
}

extern "C" void kernel_launch(void* const* d_in, const int* in_sizes, int n_in,
                              void* d_out, int out_size, void* d_ws, size_t ws_size,
                              hipStream_t stream) {
    const float* x   = (const float*)d_in[0];
    const int*   ei  = (const int*)d_in[1];
    const float* W1  = (const float*)d_in[2];
    const float* b1  = (const float*)d_in[3];
    const float* W2  = (const float*)d_in[4];
    const float* b2  = (const float*)d_in[5];
    float* out = (float*)d_out;

    const int N = in_sizes[0] / FIN;       // 100000
    const int E = in_sizes[1] / 2;         // 1600000
    const int* row = ei;
    const int* col = ei + E;

    const int NB = (N + 255) >> 8;         // 391 buckets
    const int T  = (E + TILE - 1) / TILE;  // 391 tiles
    const int EP = E + NB * 1024 + 1024;   // padded esrc capacity

    // workspace layout
    char* ws = (char*)d_ws;
    size_t off = 0;
    int*    bucketCnt = (int*)(ws + off);    off += (size_t)NB * 4;
    int*    rawBase   = (int*)(ws + off);    off += (size_t)(NB + 1) * 4;
    int*    padBase   = (int*)(ws + off);    off += (size_t)(NB + 1) * 4;
    int*    gcursor   = (int*)(ws + off);    off += (size_t)NB * 4;
    int*    deg       = (int*)(ws + off);    off += (size_t)N * 4;
    int*    rowptr    = (int*)(ws + off);    off += (size_t)N * 4;
    float*  dinv      = (float*)(ws + off);  off += (size_t)(N + 1) * 4;
    int*    pairs     = (int*)(ws + off);    off += (size_t)E * 4;
    int*    esrc      = (int*)(ws + off);    off += (size_t)EP * 4;
    __half* ew        = (__half*)(ws + off); off += (size_t)EP * 2; off = (off + 3) & ~3ull;
    __half* h1        = (__half*)(ws + off); off += (size_t)(N + 1) * H1 * 2;
    float*  agg1      = (float*)(ws + off);  off += (size_t)N * H1 * 4;
    __half* g         = (__half*)(ws + off); off += (size_t)(N + 1) * GP * 2;

    hipMemsetAsync(bucketCnt, 0, (size_t)NB * 4, stream);

    int gblocks = (N + 63) / 64;
    k_gemm1<<<gblocks, 256, 0, stream>>>(x, W1, h1, N);

    // CSR build: hist -> scan (1 block) -> chunk-claim scatter -> bucket sort -> ew
    k_hist<<<T, 256, NB * 4, stream>>>(col, E, bucketCnt, NB);
    k_scan<<<1, 512, 0, stream>>>(bucketCnt, rawBase, padBase, gcursor, dinv, NB, N);
    k_scatter<<<T, 512, 0, stream>>>(row, col, gcursor, pairs, E, NB);
    k_bucket<<<NB, 256, 0, stream>>>(pairs, rawBase, padBase, rowptr, deg, dinv, esrc, N, NB);
    k_ew<<<((size_t)N * 64 + 255) / 256, 256, 0, stream>>>(rowptr, deg, esrc, dinv, ew, N);

    // layer 1
    k_agg1<<<((size_t)N * 64 + 255) / 256, 256, 0, stream>>>(rowptr, deg, esrc, ew, h1, dinv, b1, agg1, N);

    // layer 2
    k_gemm2<<<gblocks, 256, 0, stream>>>(agg1, W2, g, N);
    k_agg2<<<((size_t)N * 64 + 255) / 256, 256, 0, stream>>>(rowptr, deg, esrc, ew, g, dinv, b2, out, N);
}

// Round 10
// 280.885 us; speedup vs baseline: 4.7309x; 1.1218x over previous
//
#include <hip/hip_runtime.h>
#include <hip/hip_fp16.h>

// GCN 2-layer forward on MI355X — R7 structure with two fusions:
//  (1) gemm1 + bucket-histogram in one kernel (blockIdx partition)
//  (2) agg1 + bias + ReLU + GEMM2 per 64-node block (LDS round-trip,
//      no global agg1 array)
// Counting-sort CSR build (chunk-claim), per-dest rows padded to x4 with
// weight-0 sentinel (node N, dinv[N]=0) => tail-free int4 edge loops.
// fp16 line-aligned gather arrays, fp32 accumulation.
// d_in: [0]=x (N*128 f32), [1]=edge_index (2*E i32), [2]=W1 (128*64),
//       [3]=b1 (64), [4]=W2 (64*40), [5]=b2 (40)
// d_out: N*40 f32

#define FIN 128
#define H1  64
#define C2  40
#define GP  64            // padded row stride (halves) for g => 128 B lines
#define TILE 8192         // edges per hist/scatter tile
#define BCAP 6144         // padded bucket capacity (mean 4096+768 pad, sd 64)

// ---------- fused GEMM1 + histogram ----------
// blocks [0, gblocks): h1 = fp16(x @ W1), 64x64 tile, 4x4/thread
// blocks [gblocks, gblocks+T): per-tile bucket histogram (bucket = dest>>8)
__global__ __launch_bounds__(256) void k_g1hist(const float* __restrict__ x,
                                                const float* __restrict__ W1,
                                                __half* __restrict__ h1, int N,
                                                const int* __restrict__ col, int E,
                                                int* __restrict__ bucketCnt, int NB,
                                                int gblocks) {
    __shared__ float smem[FIN * H1 + 64 * (FIN + 4)];   // 66560 B, aliased
    int t = threadIdx.x;

    if (blockIdx.x >= gblocks) {
        // ---- histogram path ----
        int* lh = (int*)smem;
        for (int i = t; i < NB; i += 256) lh[i] = 0;
        __syncthreads();
        int base = (blockIdx.x - gblocks) * TILE;
        int cnt = min(TILE, E - base);
        for (int i = t; i < cnt; i += 256) atomicAdd(&lh[col[base + i] >> 8], 1);
        __syncthreads();
        for (int b = t; b < NB; b += 256) if (lh[b]) atomicAdd(&bucketCnt[b], lh[b]);
        return;
    }

    // ---- GEMM1 path ----
    float* Ws = smem;                     // [k][o] 32 KB
    float (*xs)[FIN + 4] = (float (*)[FIN + 4])(smem + FIN * H1);
    int node0 = blockIdx.x * 64;

    const float4* W4 = (const float4*)W1;
    float4* Ws4 = (float4*)Ws;
#pragma unroll
    for (int j = 0; j < 8; ++j) Ws4[t + j * 256] = W4[t + j * 256];

    const float4* x4 = (const float4*)x;
#pragma unroll
    for (int j = 0; j < 8; ++j) {
        int idx = t + j * 256;
        int r = idx >> 5, kq = idx & 31;
        int node = node0 + r; if (node >= N) node = N - 1;
        float4 v = x4[(size_t)node * 32 + kq];
        *(float4*)&xs[r][kq * 4] = v;
    }
    __syncthreads();

    int og = t & 15, ng = t >> 4;
    int o0 = og * 4, n0 = ng * 4;
    float acc[4][4];
#pragma unroll
    for (int i = 0; i < 4; ++i)
#pragma unroll
        for (int j = 0; j < 4; ++j) acc[i][j] = 0.f;

#pragma unroll 8
    for (int k = 0; k < FIN; ++k) {
        float a0 = xs[n0 + 0][k], a1 = xs[n0 + 1][k];
        float a2 = xs[n0 + 2][k], a3 = xs[n0 + 3][k];
        float4 w = *(const float4*)&Ws[k * H1 + o0];
        acc[0][0] += a0 * w.x; acc[0][1] += a0 * w.y; acc[0][2] += a0 * w.z; acc[0][3] += a0 * w.w;
        acc[1][0] += a1 * w.x; acc[1][1] += a1 * w.y; acc[1][2] += a1 * w.z; acc[1][3] += a1 * w.w;
        acc[2][0] += a2 * w.x; acc[2][1] += a2 * w.y; acc[2][2] += a2 * w.z; acc[2][3] += a2 * w.w;
        acc[3][0] += a3 * w.x; acc[3][1] += a3 * w.y; acc[3][2] += a3 * w.z; acc[3][3] += a3 * w.w;
    }

#pragma unroll
    for (int i = 0; i < 4; ++i) {
        int node = node0 + n0 + i;
        if (node < N) {
            union { __half h[4]; uint2 u; } pk;
            pk.h[0] = __float2half_rn(acc[i][0]);
            pk.h[1] = __float2half_rn(acc[i][1]);
            pk.h[2] = __float2half_rn(acc[i][2]);
            pk.h[3] = __float2half_rn(acc[i][3]);
            *(uint2*)&h1[(size_t)node * H1 + o0] = pk.u;
        }
    }
}

// ---------- single-block scan over NB buckets: raw & padded bases ----------
__global__ __launch_bounds__(512) void k_scan(const int* __restrict__ bucketCnt,
                                              int* __restrict__ rawBase,
                                              int* __restrict__ padBase,
                                              int* __restrict__ gcursor,
                                              float* __restrict__ dinv,
                                              int NB, int N) {
    __shared__ int sr[512], sp[512];
    int t = threadIdx.x;
    int c = (t < NB) ? bucketCnt[t] : 0;
    int p = (t < NB) ? (((c + 3) & ~3) + 1024) : 0;   // room for per-dest x4 pad
    sr[t] = c; sp[t] = p;
    __syncthreads();
    for (int off = 1; off < 512; off <<= 1) {
        int a = (t >= off) ? sr[t - off] : 0;
        int b = (t >= off) ? sp[t - off] : 0;
        __syncthreads();
        sr[t] += a; sp[t] += b;
        __syncthreads();
    }
    if (t <= NB) {
        int rex = sr[t] - ((t < NB) ? c : 0);
        int pex = sp[t] - ((t < NB) ? p : 0);
        rawBase[t] = rex;
        padBase[t] = pex;
        if (t < NB) gcursor[t] = rex;
    }
    if (t == 0) dinv[N] = 0.f;                  // sentinel: weight 0
}

// ---------- scatter into bucket-contiguous chunks (packed pairs) ----------
// packed: bits 0..23 = src row, bits 24..31 = dest low 8
__global__ __launch_bounds__(512) void k_scatter(const int* __restrict__ row,
                                                 const int* __restrict__ col,
                                                 int* __restrict__ gcursor,
                                                 int* __restrict__ pairs,
                                                 int E, int NB) {
    __shared__ int2 stage[TILE];         // 64 KB
    __shared__ int lcnt[512];
    __shared__ int lex[512];
    __shared__ int gbase[512];
    int t = threadIdx.x, tile = blockIdx.x;
    int base = tile * TILE;
    int cnt = min(TILE, E - base);

    lcnt[t] = 0;
    __syncthreads();
    for (int i = t; i < cnt; i += 512) atomicAdd(&lcnt[col[base + i] >> 8], 1);
    __syncthreads();

    int myc = lcnt[t];
    lex[t] = myc;
    __syncthreads();
    for (int off = 1; off < 512; off <<= 1) {
        int u = (t >= off) ? lex[t - off] : 0;
        __syncthreads();
        lex[t] += u;
        __syncthreads();
    }
    int ex = lex[t] - myc;
    __syncthreads();
    lex[t] = ex;
    lcnt[t] = ex;                         // local cursor
    if (t < NB && myc > 0) gbase[t] = atomicAdd(&gcursor[t], myc);
    __syncthreads();

    for (int i = t; i < cnt; i += 512) {
        int r = row[base + i], c = col[base + i];
        int lpos = atomicAdd(&lcnt[c >> 8], 1);
        stage[lpos] = make_int2(r, c);
    }
    __syncthreads();

    for (int i = t; i < cnt; i += 512) {
        int2 p = stage[i];
        int b = p.y >> 8;
        pairs[gbase[b] + (i - lex[b])] = p.x | ((p.y & 255) << 24);
    }
}

// ---------- per-bucket final sort by dest; padded esrc segments ----------
__global__ __launch_bounds__(256) void k_bucket(const int* __restrict__ pairs,
                                                const int* __restrict__ rawBase,
                                                const int* __restrict__ padBase,
                                                int* __restrict__ rowptr,
                                                int* __restrict__ deg,
                                                float* __restrict__ dinv,
                                                int* __restrict__ esrc,
                                                int N, int NB) {
    __shared__ int dcnt[256];
    __shared__ int sr[256], sp[256];
    __shared__ int cur[256];
    __shared__ int outbuf[BCAP];         // 24 KB
    int t = threadIdx.x, b = blockIdx.x;
    int d0 = b << 8;
    int nd = min(256, N - d0);
    int bstart = rawBase[b];
    int cnt = rawBase[b + 1] - bstart;
    int pstart = padBase[b];

    dcnt[t] = 0;
    __syncthreads();
    for (int i = t; i < cnt; i += 256) {
        unsigned p = (unsigned)pairs[bstart + i];
        atomicAdd(&dcnt[p >> 24], 1);
    }
    __syncthreads();

    int myc = dcnt[t];
    int myp = (myc + 3) & ~3;            // padded per-dest count
    sr[t] = myc; sp[t] = myp;
    __syncthreads();
    for (int off = 1; off < 256; off <<= 1) {
        int a = (t >= off) ? sr[t - off] : 0;
        int c2 = (t >= off) ? sp[t - off] : 0;
        __syncthreads();
        sr[t] += a; sp[t] += c2;
        __syncthreads();
    }
    int pex = sp[t] - myp;               // exclusive padded offset
    int pcnt = sp[255];                  // total padded content
    __syncthreads();
    cur[t] = pex;
    if (t < nd) {
        int node = d0 + t;
        rowptr[node] = pstart + pex;
        deg[node] = myc;
        dinv[node] = rsqrtf((float)myc + 1.0f);
    }
    __syncthreads();

    if (pcnt <= BCAP) {
        for (int i = t; i < cnt; i += 256) {
            unsigned p = (unsigned)pairs[bstart + i];
            int lpos = atomicAdd(&cur[p >> 24], 1);
            outbuf[lpos] = (int)(p & 0xFFFFFF);
        }
        __syncthreads();
        for (int j = myc; j < myp; ++j) outbuf[pex + j] = N;   // sentinel pad
        __syncthreads();
        for (int i = t; i < pcnt; i += 256) esrc[pstart + i] = outbuf[i];
    } else {
        for (int i = t; i < cnt; i += 256) {
            unsigned p = (unsigned)pairs[bstart + i];
            int lpos = atomicAdd(&cur[p >> 24], 1);
            esrc[pstart + lpos] = (int)(p & 0xFFFFFF);
        }
        __syncthreads();
        for (int j = myc; j < myp; ++j) esrc[pstart + pex + j] = N;
    }
}

// ---------- fused agg1 + bias + ReLU + GEMM2 per 64-node block ----------
// 512 threads = 8 waves. Wave w aggregates nodes node0+w*8 .. +7 (R7 inner
// loop, lane = feature) into LDS hs[64][H1+4] with bias+ReLU applied. Then the
// block computes g = fp16(hs @ W2) with the proven register tile (2 rows x 4
// cols per thread).
__global__ __launch_bounds__(512) void k_agg1mm(const int* __restrict__ rowptr,
                                                const int* __restrict__ deg,
                                                const int* __restrict__ esrc,
                                                const __half* __restrict__ h1,
                                                const float* __restrict__ dinv,
                                                const float* __restrict__ b1,
                                                const float* __restrict__ W2,
                                                __half* __restrict__ g, int N) {
    __shared__ float hs[64][H1 + 4];     // 17 KB: relu(agg1) rows
    __shared__ float Ws[H1 * C2];        // 10 KB, [k][c]
    int t = threadIdx.x;
    int node0 = blockIdx.x * 64;

    {   // stage W2: 640 float4
        const float4* W4 = (const float4*)W2;
        float4* Ws4 = (float4*)Ws;
        for (int i = t; i < 640; i += 512) Ws4[i] = W4[i];
    }

    int wv = t >> 6, lane = t & 63;
    float b1v = b1[lane];

    // aggregation: 8 nodes per wave, sequential
    for (int j = 0; j < 8; ++j) {
        int r = wv * 8 + j;
        int node = node0 + r;
        if (node >= N) { hs[r][lane] = 0.f; continue; }
        int start = rowptr[node], d = deg[node];
        int d4 = (d + 3) & ~3;
        float dc = dinv[node];
        float acc = dc * dc * __half2float(h1[(size_t)node * H1 + lane]);
        int i = 0;
        for (; i + 8 <= d4; i += 8) {
            int4 ra = *(const int4*)&esrc[start + i];
            int4 rb = *(const int4*)&esrc[start + i + 4];
            float w0 = dinv[ra.x] * dc, w1 = dinv[ra.y] * dc;
            float w2 = dinv[ra.z] * dc, w3 = dinv[ra.w] * dc;
            float w4 = dinv[rb.x] * dc, w5 = dinv[rb.y] * dc;
            float w6 = dinv[rb.z] * dc, w7 = dinv[rb.w] * dc;
            float v0 = __half2float(h1[(size_t)ra.x * H1 + lane]);
            float v1 = __half2float(h1[(size_t)ra.y * H1 + lane]);
            float v2 = __half2float(h1[(size_t)ra.z * H1 + lane]);
            float v3 = __half2float(h1[(size_t)ra.w * H1 + lane]);
            float v4 = __half2float(h1[(size_t)rb.x * H1 + lane]);
            float v5 = __half2float(h1[(size_t)rb.y * H1 + lane]);
            float v6 = __half2float(h1[(size_t)rb.z * H1 + lane]);
            float v7 = __half2float(h1[(size_t)rb.w * H1 + lane]);
            acc += w0 * v0 + w1 * v1 + w2 * v2 + w3 * v3;
            acc += w4 * v4 + w5 * v5 + w6 * v6 + w7 * v7;
        }
        if (i < d4) {
            int4 ra = *(const int4*)&esrc[start + i];
            float w0 = dinv[ra.x] * dc, w1 = dinv[ra.y] * dc;
            float w2 = dinv[ra.z] * dc, w3 = dinv[ra.w] * dc;
            float v0 = __half2float(h1[(size_t)ra.x * H1 + lane]);
            float v1 = __half2float(h1[(size_t)ra.y * H1 + lane]);
            float v2 = __half2float(h1[(size_t)ra.z * H1 + lane]);
            float v3 = __half2float(h1[(size_t)ra.w * H1 + lane]);
            acc += w0 * v0 + w1 * v1 + w2 * v2 + w3 * v3;
        }
        hs[r][lane] = fmaxf(acc + b1v, 0.f);   // bias + ReLU
    }
    __syncthreads();

    // GEMM2 from LDS: 512 threads = 16 col-groups x 32 row-groups (2 rows each)
    int og = t & 15, ng = t >> 4;
    int o0 = og * 4, n0 = ng * 2;
    int o0c = (o0 <= 36) ? o0 : 36;
    float acc[2][4];
#pragma unroll
    for (int i = 0; i < 2; ++i)
#pragma unroll
        for (int j = 0; j < 4; ++j) acc[i][j] = 0.f;

#pragma unroll 8
    for (int k = 0; k < H1; ++k) {
        float a0 = hs[n0 + 0][k], a1 = hs[n0 + 1][k];
        float4 w = *(const float4*)&Ws[k * C2 + o0c];
        acc[0][0] += a0 * w.x; acc[0][1] += a0 * w.y; acc[0][2] += a0 * w.z; acc[0][3] += a0 * w.w;
        acc[1][0] += a1 * w.x; acc[1][1] += a1 * w.y; acc[1][2] += a1 * w.z; acc[1][3] += a1 * w.w;
    }

    if (o0 < C2) {
#pragma unroll
        for (int i = 0; i < 2; ++i) {
            int node = node0 + n0 + i;
            if (node < N) {
                union { __half h[4]; uint2 u; } pk;
                pk.h[0] = __float2half_rn(acc[i][0]);
                pk.h[1] = __float2half_rn(acc[i][1]);
                pk.h[2] = __float2half_rn(acc[i][2]);
                pk.h[3] = __float2half_rn(acc[i][3]);
                *(uint2*)&g[(size_t)node * GP + o0] = pk.u;
            }
        }
    }
}

// ---------- agg2: wave per node, lanes 0..39; int4 edge loop ----------
__global__ __launch_bounds__(256) void k_agg2(const int* __restrict__ rowptr,
                                              const int* __restrict__ deg,
                                              const int* __restrict__ esrc,
                                              const __half* __restrict__ g,
                                              const float* __restrict__ dinv,
                                              const float* __restrict__ b2,
                                              float* __restrict__ out, int N) {
    int w = (blockIdx.x * blockDim.x + threadIdx.x) >> 6;
    int lane = threadIdx.x & 63;
    if (w >= N || lane >= C2) return;
    int start = rowptr[w], d = deg[w];
    int d4 = (d + 3) & ~3;
    float dc = dinv[w];
    float acc = dc * dc * __half2float(g[(size_t)w * GP + lane]);
    int i = 0;
    for (; i + 8 <= d4; i += 8) {
        int4 ra = *(const int4*)&esrc[start + i];
        int4 rb = *(const int4*)&esrc[start + i + 4];
        float w0 = dinv[ra.x] * dc, w1 = dinv[ra.y] * dc;
        float w2 = dinv[ra.z] * dc, w3 = dinv[ra.w] * dc;
        float w4 = dinv[rb.x] * dc, w5 = dinv[rb.y] * dc;
        float w6 = dinv[rb.z] * dc, w7 = dinv[rb.w] * dc;
        float v0 = __half2float(g[(size_t)ra.x * GP + lane]);
        float v1 = __half2float(g[(size_t)ra.y * GP + lane]);
        float v2 = __half2float(g[(size_t)ra.z * GP + lane]);
        float v3 = __half2float(g[(size_t)ra.w * GP + lane]);
        float v4 = __half2float(g[(size_t)rb.x * GP + lane]);
        float v5 = __half2float(g[(size_t)rb.y * GP + lane]);
        float v6 = __half2float(g[(size_t)rb.z * GP + lane]);
        float v7 = __half2float(g[(size_t)rb.w * GP + lane]);
        acc += w0 * v0 + w1 * v1 + w2 * v2 + w3 * v3;
        acc += w4 * v4 + w5 * v5 + w6 * v6 + w7 * v7;
    }
    if (i < d4) {
        int4 ra = *(const int4*)&esrc[start + i];
        float w0 = dinv[ra.x] * dc, w1 = dinv[ra.y] * dc;
        float w2 = dinv[ra.z] * dc, w3 = dinv[ra.w] * dc;
        float v0 = __half2float(g[(size_t)ra.x * GP + lane]);
        float v1 = __half2float(g[(size_t)ra.y * GP + lane]);
        float v2 = __half2float(g[(size_t)ra.z * GP + lane]);
        float v3 = __half2float(g[(size_t)ra.w * GP + lane]);
        acc += w0 * v0 + w1 * v1 + w2 * v2 + w3 * v3;
    }
    out[(size_t)w * C2 + lane] = acc + b2[lane];
}

extern "C" void kernel_launch(void* const* d_in, const int* in_sizes, int n_in,
                              void* d_out, int out_size, void* d_ws, size_t ws_size,
                              hipStream_t stream) {
    const float* x   = (const float*)d_in[0];
    const int*   ei  = (const int*)d_in[1];
    const float* W1  = (const float*)d_in[2];
    const float* b1  = (const float*)d_in[3];
    const float* W2  = (const float*)d_in[4];
    const float* b2  = (const float*)d_in[5];
    float* out = (float*)d_out;

    const int N = in_sizes[0] / FIN;       // 100000
    const int E = in_sizes[1] / 2;         // 1600000
    const int* row = ei;
    const int* col = ei + E;

    const int NB = (N + 255) >> 8;         // 391 buckets
    const int T  = (E + TILE - 1) / TILE;  // 196 tiles
    const int EP = E + NB * 1024 + 1024;   // padded esrc capacity

    // workspace layout
    char* ws = (char*)d_ws;
    size_t off = 0;
    int*    bucketCnt = (int*)(ws + off);    off += (size_t)NB * 4;
    int*    rawBase   = (int*)(ws + off);    off += (size_t)(NB + 1) * 4;
    int*    padBase   = (int*)(ws + off);    off += (size_t)(NB + 1) * 4;
    int*    gcursor   = (int*)(ws + off);    off += (size_t)NB * 4;
    int*    deg       = (int*)(ws + off);    off += (size_t)N * 4;
    int*    rowptr    = (int*)(ws + off);    off += (size_t)N * 4;
    float*  dinv      = (float*)(ws + off);  off += (size_t)(N + 1) * 4;
    int*    pairs     = (int*)(ws + off);    off += (size_t)E * 4;
    int*    esrc      = (int*)(ws + off);    off += (size_t)EP * 4;
    __half* h1        = (__half*)(ws + off); off += (size_t)(N + 1) * H1 * 2;
    __half* g         = (__half*)(ws + off); off += (size_t)(N + 1) * GP * 2;

    hipMemsetAsync(bucketCnt, 0, (size_t)NB * 4, stream);

    int gblocks = (N + 63) / 64;           // 1563

    // fused GEMM1 + histogram (independent work, one dispatch)
    k_g1hist<<<gblocks + T, 256, 0, stream>>>(x, W1, h1, N, col, E, bucketCnt, NB, gblocks);

    // CSR build: scan (1 block) -> chunk-claim scatter -> bucket sort
    k_scan<<<1, 512, 0, stream>>>(bucketCnt, rawBase, padBase, gcursor, dinv, NB, N);
    k_scatter<<<T, 512, 0, stream>>>(row, col, gcursor, pairs, E, NB);
    k_bucket<<<NB, 256, 0, stream>>>(pairs, rawBase, padBase, rowptr, deg, dinv, esrc, N, NB);

    // layer 1 aggregation + bias + ReLU + GEMM2 (fused, no global agg1)
    k_agg1mm<<<gblocks, 512, 0, stream>>>(rowptr, deg, esrc, h1, dinv, b1, W2, g, N);

    // layer 2 aggregation + bias
    k_agg2<<<((size_t)N * 64 + 255) / 256, 256, 0, stream>>>(rowptr, deg, esrc, g, dinv, b2, out, N);
}

// Round 11
// 277.012 us; speedup vs baseline: 4.7970x; 1.0140x over previous
//
#include <hip/hip_runtime.h>
#include <hip/hip_fp16.h>

// GCN 2-layer forward on MI355X — R10 structure + half2 feature-pair lanes in
// the aggregation loops (2 edges per wave VMEM instruction, halved VALU).
//  (1) gemm1 + bucket-histogram in one kernel (blockIdx partition)
//  (2) agg1 + bias + ReLU + GEMM2 per 64-node block (LDS round-trip)
// Counting-sort CSR build (chunk-claim), per-dest rows padded to x4 with
// weight-0 sentinel (node N, dinv[N]=0). fp16 line-aligned gather arrays,
// fp32 accumulation.
// d_in: [0]=x (N*128 f32), [1]=edge_index (2*E i32), [2]=W1 (128*64),
//       [3]=b1 (64), [4]=W2 (64*40), [5]=b2 (40)
// d_out: N*40 f32

#define FIN 128
#define H1  64
#define C2  40
#define GP  64            // padded row stride (halves) for g => 128 B lines
#define TILE 8192         // edges per hist/scatter tile
#define BCAP 6144         // padded bucket capacity (mean 4096+768 pad, sd 64)

// ---------- fused GEMM1 + histogram ----------
__global__ __launch_bounds__(256) void k_g1hist(const float* __restrict__ x,
                                                const float* __restrict__ W1,
                                                __half* __restrict__ h1, int N,
                                                const int* __restrict__ col, int E,
                                                int* __restrict__ bucketCnt, int NB,
                                                int gblocks) {
    __shared__ float smem[FIN * H1 + 64 * (FIN + 4)];   // 66560 B, aliased
    int t = threadIdx.x;

    if (blockIdx.x >= gblocks) {
        // ---- histogram path ----
        int* lh = (int*)smem;
        for (int i = t; i < NB; i += 256) lh[i] = 0;
        __syncthreads();
        int base = (blockIdx.x - gblocks) * TILE;
        int cnt = min(TILE, E - base);
        for (int i = t; i < cnt; i += 256) atomicAdd(&lh[col[base + i] >> 8], 1);
        __syncthreads();
        for (int b = t; b < NB; b += 256) if (lh[b]) atomicAdd(&bucketCnt[b], lh[b]);
        return;
    }

    // ---- GEMM1 path ----
    float* Ws = smem;                     // [k][o] 32 KB
    float (*xs)[FIN + 4] = (float (*)[FIN + 4])(smem + FIN * H1);
    int node0 = blockIdx.x * 64;

    const float4* W4 = (const float4*)W1;
    float4* Ws4 = (float4*)Ws;
#pragma unroll
    for (int j = 0; j < 8; ++j) Ws4[t + j * 256] = W4[t + j * 256];

    const float4* x4 = (const float4*)x;
#pragma unroll
    for (int j = 0; j < 8; ++j) {
        int idx = t + j * 256;
        int r = idx >> 5, kq = idx & 31;
        int node = node0 + r; if (node >= N) node = N - 1;
        float4 v = x4[(size_t)node * 32 + kq];
        *(float4*)&xs[r][kq * 4] = v;
    }
    __syncthreads();

    int og = t & 15, ng = t >> 4;
    int o0 = og * 4, n0 = ng * 4;
    float acc[4][4];
#pragma unroll
    for (int i = 0; i < 4; ++i)
#pragma unroll
        for (int j = 0; j < 4; ++j) acc[i][j] = 0.f;

#pragma unroll 8
    for (int k = 0; k < FIN; ++k) {
        float a0 = xs[n0 + 0][k], a1 = xs[n0 + 1][k];
        float a2 = xs[n0 + 2][k], a3 = xs[n0 + 3][k];
        float4 w = *(const float4*)&Ws[k * H1 + o0];
        acc[0][0] += a0 * w.x; acc[0][1] += a0 * w.y; acc[0][2] += a0 * w.z; acc[0][3] += a0 * w.w;
        acc[1][0] += a1 * w.x; acc[1][1] += a1 * w.y; acc[1][2] += a1 * w.z; acc[1][3] += a1 * w.w;
        acc[2][0] += a2 * w.x; acc[2][1] += a2 * w.y; acc[2][2] += a2 * w.z; acc[2][3] += a2 * w.w;
        acc[3][0] += a3 * w.x; acc[3][1] += a3 * w.y; acc[3][2] += a3 * w.z; acc[3][3] += a3 * w.w;
    }

#pragma unroll
    for (int i = 0; i < 4; ++i) {
        int node = node0 + n0 + i;
        if (node < N) {
            union { __half h[4]; uint2 u; } pk;
            pk.h[0] = __float2half_rn(acc[i][0]);
            pk.h[1] = __float2half_rn(acc[i][1]);
            pk.h[2] = __float2half_rn(acc[i][2]);
            pk.h[3] = __float2half_rn(acc[i][3]);
            *(uint2*)&h1[(size_t)node * H1 + o0] = pk.u;
        }
    }
}

// ---------- single-block scan over NB buckets: raw & padded bases ----------
__global__ __launch_bounds__(512) void k_scan(const int* __restrict__ bucketCnt,
                                              int* __restrict__ rawBase,
                                              int* __restrict__ padBase,
                                              int* __restrict__ gcursor,
                                              float* __restrict__ dinv,
                                              int NB, int N) {
    __shared__ int sr[512], sp[512];
    int t = threadIdx.x;
    int c = (t < NB) ? bucketCnt[t] : 0;
    int p = (t < NB) ? (((c + 3) & ~3) + 1024) : 0;   // room for per-dest x4 pad
    sr[t] = c; sp[t] = p;
    __syncthreads();
    for (int off = 1; off < 512; off <<= 1) {
        int a = (t >= off) ? sr[t - off] : 0;
        int b = (t >= off) ? sp[t - off] : 0;
        __syncthreads();
        sr[t] += a; sp[t] += b;
        __syncthreads();
    }
    if (t <= NB) {
        int rex = sr[t] - ((t < NB) ? c : 0);
        int pex = sp[t] - ((t < NB) ? p : 0);
        rawBase[t] = rex;
        padBase[t] = pex;
        if (t < NB) gcursor[t] = rex;
    }
    if (t == 0) dinv[N] = 0.f;                  // sentinel: weight 0
}

// ---------- scatter into bucket-contiguous chunks (packed pairs) ----------
// packed: bits 0..23 = src row, bits 24..31 = dest low 8
__global__ __launch_bounds__(512) void k_scatter(const int* __restrict__ row,
                                                 const int* __restrict__ col,
                                                 int* __restrict__ gcursor,
                                                 int* __restrict__ pairs,
                                                 int E, int NB) {
    __shared__ int2 stage[TILE];         // 64 KB
    __shared__ int lcnt[512];
    __shared__ int lex[512];
    __shared__ int gbase[512];
    int t = threadIdx.x, tile = blockIdx.x;
    int base = tile * TILE;
    int cnt = min(TILE, E - base);

    lcnt[t] = 0;
    __syncthreads();
    for (int i = t; i < cnt; i += 512) atomicAdd(&lcnt[col[base + i] >> 8], 1);
    __syncthreads();

    int myc = lcnt[t];
    lex[t] = myc;
    __syncthreads();
    for (int off = 1; off < 512; off <<= 1) {
        int u = (t >= off) ? lex[t - off] : 0;
        __syncthreads();
        lex[t] += u;
        __syncthreads();
    }
    int ex = lex[t] - myc;
    __syncthreads();
    lex[t] = ex;
    lcnt[t] = ex;                         // local cursor
    if (t < NB && myc > 0) gbase[t] = atomicAdd(&gcursor[t], myc);
    __syncthreads();

    for (int i = t; i < cnt; i += 512) {
        int r = row[base + i], c = col[base + i];
        int lpos = atomicAdd(&lcnt[c >> 8], 1);
        stage[lpos] = make_int2(r, c);
    }
    __syncthreads();

    for (int i = t; i < cnt; i += 512) {
        int2 p = stage[i];
        int b = p.y >> 8;
        pairs[gbase[b] + (i - lex[b])] = p.x | ((p.y & 255) << 24);
    }
}

// ---------- per-bucket final sort by dest; padded esrc segments (512 thr) ----------
__global__ __launch_bounds__(512) void k_bucket(const int* __restrict__ pairs,
                                                const int* __restrict__ rawBase,
                                                const int* __restrict__ padBase,
                                                int* __restrict__ rowptr,
                                                int* __restrict__ deg,
                                                float* __restrict__ dinv,
                                                int* __restrict__ esrc,
                                                int N, int NB) {
    __shared__ int dcnt[256];
    __shared__ int sr[256], sp[256];
    __shared__ int cur[256];
    __shared__ int outbuf[BCAP];         // 24 KB
    int t = threadIdx.x, b = blockIdx.x;
    int d0 = b << 8;
    int nd = min(256, N - d0);
    int bstart = rawBase[b];
    int cnt = rawBase[b + 1] - bstart;
    int pstart = padBase[b];

    if (t < 256) dcnt[t] = 0;
    __syncthreads();
    for (int i = t; i < cnt; i += 512) {
        unsigned p = (unsigned)pairs[bstart + i];
        atomicAdd(&dcnt[p >> 24], 1);
    }
    __syncthreads();

    int myc = 0, myp = 0;
    if (t < 256) {
        myc = dcnt[t];
        myp = (myc + 3) & ~3;
        sr[t] = myc; sp[t] = myp;
    }
    __syncthreads();
    for (int off = 1; off < 256; off <<= 1) {
        int a = 0, c2 = 0;
        if (t < 256 && t >= off) { a = sr[t - off]; c2 = sp[t - off]; }
        __syncthreads();
        if (t < 256) { sr[t] += a; sp[t] += c2; }
        __syncthreads();
    }
    if (t < 256) {
        int pex = sp[t] - myp;
        cur[t] = pex;
        if (t < nd) {
            int node = d0 + t;
            rowptr[node] = pstart + pex;
            deg[node] = myc;
            dinv[node] = rsqrtf((float)myc + 1.0f);
        }
    }
    __syncthreads();
    int pcnt = sp[255];

    if (pcnt <= BCAP) {
        for (int i = t; i < cnt; i += 512) {
            unsigned p = (unsigned)pairs[bstart + i];
            int lpos = atomicAdd(&cur[p >> 24], 1);
            outbuf[lpos] = (int)(p & 0xFFFFFF);
        }
        __syncthreads();
        if (t < 256) {
            int pex = sp[t] - myp;
            for (int j = myc; j < myp; ++j) outbuf[pex + j] = N;   // sentinel pad
        }
        __syncthreads();
        for (int i = t; i < pcnt; i += 512) esrc[pstart + i] = outbuf[i];
    } else {
        for (int i = t; i < cnt; i += 512) {
            unsigned p = (unsigned)pairs[bstart + i];
            int lpos = atomicAdd(&cur[p >> 24], 1);
            esrc[pstart + lpos] = (int)(p & 0xFFFFFF);
        }
        __syncthreads();
        if (t < 256) {
            int pex = sp[t] - myp;
            for (int j = myc; j < myp; ++j) esrc[pstart + pex + j] = N;
        }
    }
}

// ---------- fused agg1 + bias + ReLU + GEMM2 per 64-node block ----------
// 512 threads = 8 waves. Aggregation: lane = (edge-half, feature-pair):
// lanes 0-31 process even edges, 32-63 odd edges; each lane loads __half2
// (features 2f, 2f+1). Cross-half __shfl reduce. Then block GEMM2 from LDS.
__global__ __launch_bounds__(512) void k_agg1mm(const int* __restrict__ rowptr,
                                                const int* __restrict__ deg,
                                                const int* __restrict__ esrc,
                                                const __half* __restrict__ h1,
                                                const float* __restrict__ dinv,
                                                const float* __restrict__ b1,
                                                const float* __restrict__ W2,
                                                __half* __restrict__ g, int N) {
    __shared__ float hs[64][H1 + 4];     // 17 KB: relu(agg1) rows
    __shared__ float Ws[H1 * C2];        // 10 KB, [k][c]
    int t = threadIdx.x;
    int node0 = blockIdx.x * 64;

    {   // stage W2: 640 float4
        const float4* W4 = (const float4*)W2;
        float4* Ws4 = (float4*)Ws;
        for (int i = t; i < 640; i += 512) Ws4[i] = W4[i];
    }

    int wv = t >> 6, lane = t & 63;
    int half = lane >> 5;                // which edge of a pair
    int f = lane & 31;                   // feature-pair index
    float2 b1v = *(const float2*)&b1[2 * f];

    // aggregation: 8 nodes per wave, sequential
    for (int j = 0; j < 8; ++j) {
        int r = wv * 8 + j;
        int node = node0 + r;
        if (node >= N) { if (lane < 32) { hs[r][2*f] = 0.f; hs[r][2*f+1] = 0.f; } continue; }
        int start = rowptr[node], d = deg[node];
        int d4 = (d + 3) & ~3;
        float dc = dinv[node];
        float ax = 0.f, ay = 0.f;
        int i = 0;
        for (; i + 8 <= d4; i += 8) {
            int e0 = start + i + half;
            int s0 = esrc[e0], s1 = esrc[e0 + 2], s2 = esrc[e0 + 4], s3 = esrc[e0 + 6];
            float w0 = dinv[s0] * dc, w1 = dinv[s1] * dc;
            float w2 = dinv[s2] * dc, w3 = dinv[s3] * dc;
            float2 v0 = __half22float2(*(const __half2*)&h1[(size_t)s0 * H1 + 2 * f]);
            float2 v1 = __half22float2(*(const __half2*)&h1[(size_t)s1 * H1 + 2 * f]);
            float2 v2 = __half22float2(*(const __half2*)&h1[(size_t)s2 * H1 + 2 * f]);
            float2 v3 = __half22float2(*(const __half2*)&h1[(size_t)s3 * H1 + 2 * f]);
            ax += w0 * v0.x + w1 * v1.x + w2 * v2.x + w3 * v3.x;
            ay += w0 * v0.y + w1 * v1.y + w2 * v2.y + w3 * v3.y;
        }
        if (i < d4) {                    // 4-edge tail: 2 per half
            int e0 = start + i + half;
            int s0 = esrc[e0], s1 = esrc[e0 + 2];
            float w0 = dinv[s0] * dc, w1 = dinv[s1] * dc;
            float2 v0 = __half22float2(*(const __half2*)&h1[(size_t)s0 * H1 + 2 * f]);
            float2 v1 = __half22float2(*(const __half2*)&h1[(size_t)s1 * H1 + 2 * f]);
            ax += w0 * v0.x + w1 * v1.x;
            ay += w0 * v0.y + w1 * v1.y;
        }
        // cross-half reduce (both halves end with full sum)
        ax += __shfl(ax, lane ^ 32);
        ay += __shfl(ay, lane ^ 32);
        // self-loop + bias + ReLU
        float2 sv = __half22float2(*(const __half2*)&h1[(size_t)node * H1 + 2 * f]);
        ax = fmaxf(ax + dc * dc * sv.x + b1v.x, 0.f);
        ay = fmaxf(ay + dc * dc * sv.y + b1v.y, 0.f);
        if (lane < 32) { hs[r][2 * f] = ax; hs[r][2 * f + 1] = ay; }
    }
    __syncthreads();

    // GEMM2 from LDS: 512 threads = 16 col-groups x 32 row-groups (2 rows each)
    int og = t & 15, ng = t >> 4;
    int o0 = og * 4, n0 = ng * 2;
    int o0c = (o0 <= 36) ? o0 : 36;
    float acc[2][4];
#pragma unroll
    for (int i = 0; i < 2; ++i)
#pragma unroll
        for (int j = 0; j < 4; ++j) acc[i][j] = 0.f;

#pragma unroll 8
    for (int k = 0; k < H1; ++k) {
        float a0 = hs[n0 + 0][k], a1 = hs[n0 + 1][k];
        float4 w = *(const float4*)&Ws[k * C2 + o0c];
        acc[0][0] += a0 * w.x; acc[0][1] += a0 * w.y; acc[0][2] += a0 * w.z; acc[0][3] += a0 * w.w;
        acc[1][0] += a1 * w.x; acc[1][1] += a1 * w.y; acc[1][2] += a1 * w.z; acc[1][3] += a1 * w.w;
    }

    if (o0 < C2) {
#pragma unroll
        for (int i = 0; i < 2; ++i) {
            int node = node0 + n0 + i;
            if (node < N) {
                union { __half h[4]; uint2 u; } pk;
                pk.h[0] = __float2half_rn(acc[i][0]);
                pk.h[1] = __float2half_rn(acc[i][1]);
                pk.h[2] = __float2half_rn(acc[i][2]);
                pk.h[3] = __float2half_rn(acc[i][3]);
                *(uint2*)&g[(size_t)node * GP + o0] = pk.u;
            }
        }
    }
}

// ---------- agg2: wave per node, half2 feature-pair lanes (f<20 active) ----------
__global__ __launch_bounds__(256) void k_agg2(const int* __restrict__ rowptr,
                                              const int* __restrict__ deg,
                                              const int* __restrict__ esrc,
                                              const __half* __restrict__ g,
                                              const float* __restrict__ dinv,
                                              const float* __restrict__ b2,
                                              float* __restrict__ out, int N) {
    int w = (blockIdx.x * blockDim.x + threadIdx.x) >> 6;
    int lane = threadIdx.x & 63;
    if (w >= N) return;
    int half = lane >> 5;
    int f = lane & 31;                   // feature-pair; active f<20
    bool act = f < 20;
    float2 b2v = act ? *(const float2*)&b2[2 * f] : make_float2(0.f, 0.f);

    int start = rowptr[w], d = deg[w];
    int d4 = (d + 3) & ~3;
    float dc = dinv[w];
    float ax = 0.f, ay = 0.f;
    int i = 0;
    for (; i + 8 <= d4; i += 8) {
        int e0 = start + i + half;
        int s0 = esrc[e0], s1 = esrc[e0 + 2], s2 = esrc[e0 + 4], s3 = esrc[e0 + 6];
        float w0 = dinv[s0] * dc, w1 = dinv[s1] * dc;
        float w2 = dinv[s2] * dc, w3 = dinv[s3] * dc;
        float2 v0 = __half22float2(*(const __half2*)&g[(size_t)s0 * GP + 2 * f]);
        float2 v1 = __half22float2(*(const __half2*)&g[(size_t)s1 * GP + 2 * f]);
        float2 v2 = __half22float2(*(const __half2*)&g[(size_t)s2 * GP + 2 * f]);
        float2 v3 = __half22float2(*(const __half2*)&g[(size_t)s3 * GP + 2 * f]);
        ax += w0 * v0.x + w1 * v1.x + w2 * v2.x + w3 * v3.x;
        ay += w0 * v0.y + w1 * v1.y + w2 * v2.y + w3 * v3.y;
    }
    if (i < d4) {
        int e0 = start + i + half;
        int s0 = esrc[e0], s1 = esrc[e0 + 2];
        float w0 = dinv[s0] * dc, w1 = dinv[s1] * dc;
        float2 v0 = __half22float2(*(const __half2*)&g[(size_t)s0 * GP + 2 * f]);
        float2 v1 = __half22float2(*(const __half2*)&g[(size_t)s1 * GP + 2 * f]);
        ax += w0 * v0.x + w1 * v1.x;
        ay += w0 * v0.y + w1 * v1.y;
    }
    ax += __shfl(ax, lane ^ 32);
    ay += __shfl(ay, lane ^ 32);
    if (lane < 32 && act) {
        float2 sv = __half22float2(*(const __half2*)&g[(size_t)w * GP + 2 * f]);
        float2 o;
        o.x = ax + dc * dc * sv.x + b2v.x;
        o.y = ay + dc * dc * sv.y + b2v.y;
        *(float2*)&out[(size_t)w * C2 + 2 * f] = o;
    }
}

extern "C" void kernel_launch(void* const* d_in, const int* in_sizes, int n_in,
                              void* d_out, int out_size, void* d_ws, size_t ws_size,
                              hipStream_t stream) {
    const float* x   = (const float*)d_in[0];
    const int*   ei  = (const int*)d_in[1];
    const float* W1  = (const float*)d_in[2];
    const float* b1  = (const float*)d_in[3];
    const float* W2  = (const float*)d_in[4];
    const float* b2  = (const float*)d_in[5];
    float* out = (float*)d_out;

    const int N = in_sizes[0] / FIN;       // 100000
    const int E = in_sizes[1] / 2;         // 1600000
    const int* row = ei;
    const int* col = ei + E;

    const int NB = (N + 255) >> 8;         // 391 buckets
    const int T  = (E + TILE - 1) / TILE;  // 196 tiles
    const int EP = E + NB * 1024 + 1024;   // padded esrc capacity

    // workspace layout
    char* ws = (char*)d_ws;
    size_t off = 0;
    int*    bucketCnt = (int*)(ws + off);    off += (size_t)NB * 4;
    int*    rawBase   = (int*)(ws + off);    off += (size_t)(NB + 1) * 4;
    int*    padBase   = (int*)(ws + off);    off += (size_t)(NB + 1) * 4;
    int*    gcursor   = (int*)(ws + off);    off += (size_t)NB * 4;
    int*    deg       = (int*)(ws + off);    off += (size_t)N * 4;
    int*    rowptr    = (int*)(ws + off);    off += (size_t)N * 4;
    float*  dinv      = (float*)(ws + off);  off += (size_t)(N + 1) * 4;
    int*    pairs     = (int*)(ws + off);    off += (size_t)E * 4;
    int*    esrc      = (int*)(ws + off);    off += (size_t)EP * 4;
    __half* h1        = (__half*)(ws + off); off += (size_t)(N + 1) * H1 * 2;
    __half* g         = (__half*)(ws + off); off += (size_t)(N + 1) * GP * 2;

    hipMemsetAsync(bucketCnt, 0, (size_t)NB * 4, stream);

    int gblocks = (N + 63) / 64;           // 1563

    // fused GEMM1 + histogram
    k_g1hist<<<gblocks + T, 256, 0, stream>>>(x, W1, h1, N, col, E, bucketCnt, NB, gblocks);

    // CSR build: scan (1 block) -> chunk-claim scatter -> bucket sort
    k_scan<<<1, 512, 0, stream>>>(bucketCnt, rawBase, padBase, gcursor, dinv, NB, N);
    k_scatter<<<T, 512, 0, stream>>>(row, col, gcursor, pairs, E, NB);
    k_bucket<<<NB, 512, 0, stream>>>(pairs, rawBase, padBase, rowptr, deg, dinv, esrc, N, NB);

    // layer 1 aggregation + bias + ReLU + GEMM2 (fused)
    k_agg1mm<<<gblocks, 512, 0, stream>>>(rowptr, deg, esrc, h1, dinv, b1, W2, g, N);

    // layer 2 aggregation + bias
    k_agg2<<<((size_t)N * 64 + 255) / 256, 256, 0, stream>>>(rowptr, deg, esrc, g, dinv, b2, out, N);
}